// Round 1
// baseline (85.208 us; speedup 1.0000x reference)
//
#include <hip/hip_runtime.h>

// SSIM loss, fused: 2x2 avg-pool + separable 11x11 Gaussian convs + SSIM + reduce.
// Input: x,y f32 [32,3,512,512]. Output: scalar f32 = 1 - mean(SSIM map).
// Pooled plane: 256x256; conv VALID output: 246x246; planes = 32*3 = 96.

#define TILE 32      // output tile per block
#define HALO 10      // KS-1
#define PT   42      // pooled tile = TILE+HALO
#define KS   11
#define POOLD 256
#define OUTD 246
#define NPLANE 96
#define NBLK (8*8*NPLANE)   // 6144

__global__ __launch_bounds__(256) void ssim_kernel(const float* __restrict__ x,
                                                   const float* __restrict__ y,
                                                   double* __restrict__ partial) {
    __shared__ float xs[PT][PT + 2];           // pooled x tile (pad stride 44)
    __shared__ float ys[PT][PT + 2];           // pooled y tile
    __shared__ float hb[5][PT][TILE + 1];      // horizontal partial sums (pad 33)
    __shared__ float wred[4];

    const int tid = threadIdx.x;
    const int plane = blockIdx.z;
    const int oy0 = blockIdx.y * TILE;
    const int ox0 = blockIdx.x * TILE;
    const float* xp = x + (size_t)plane * 512 * 512;
    const float* yp = y + (size_t)plane * 512 * 512;

    // normalized 1D Gaussian weights (separable kernel)
    float w[KS];
    {
        float s = 0.f;
        #pragma unroll
        for (int i = 0; i < KS; ++i) {
            float d = (float)i - 5.f;
            w[i] = expf(-d * d / 4.5f);   // 2*sigma^2 = 4.5
            s += w[i];
        }
        float inv = 1.f / s;
        #pragma unroll
        for (int i = 0; i < KS; ++i) w[i] *= inv;
    }

    // ---- stage pooled 42x42 tile: each iter handles 2 pooled pixels via float4 ----
    for (int p = tid; p < PT * 21; p += 256) {
        int pr = p / 21, pq = p % 21;
        int gr = oy0 + pr;           // pooled row (may exceed 255 on edge tiles)
        int gc0 = ox0 + 2 * pq;      // pooled col (even)
        float x0 = 0.f, x1 = 0.f, y0 = 0.f, y1 = 0.f;
        if (gr < POOLD && gc0 < POOLD) {
            const float4 a0 = *(const float4*)(xp + (size_t)(2 * gr) * 512 + 2 * gc0);
            const float4 a1 = *(const float4*)(xp + (size_t)(2 * gr + 1) * 512 + 2 * gc0);
            x0 = (a0.x + a0.y + a1.x + a1.y) * 0.25f;
            x1 = (a0.z + a0.w + a1.z + a1.w) * 0.25f;
            const float4 b0 = *(const float4*)(yp + (size_t)(2 * gr) * 512 + 2 * gc0);
            const float4 b1 = *(const float4*)(yp + (size_t)(2 * gr + 1) * 512 + 2 * gc0);
            y0 = (b0.x + b0.y + b1.x + b1.y) * 0.25f;
            y1 = (b0.z + b0.w + b1.z + b1.w) * 0.25f;
        }
        xs[pr][2 * pq]     = x0;
        xs[pr][2 * pq + 1] = x1;
        ys[pr][2 * pq]     = y0;
        ys[pr][2 * pq + 1] = y1;
    }
    __syncthreads();

    // ---- horizontal pass: 42 rows x 32 cols, 5 accumulators ----
    for (int p = tid; p < PT * TILE; p += 256) {
        int r = p / TILE, c = p % TILE;
        float mx = 0.f, my = 0.f, xx = 0.f, yy = 0.f, xy = 0.f;
        #pragma unroll
        for (int k = 0; k < KS; ++k) {
            float wk = w[k];
            float xv = xs[r][c + k];
            float yv = ys[r][c + k];
            mx += wk * xv;
            my += wk * yv;
            xx += wk * xv * xv;
            yy += wk * yv * yv;
            xy += wk * xv * yv;
        }
        hb[0][r][c] = mx;
        hb[1][r][c] = my;
        hb[2][r][c] = xx;
        hb[3][r][c] = yy;
        hb[4][r][c] = xy;
    }
    __syncthreads();

    // ---- vertical pass + SSIM formula ----
    const float c1 = 1e-4f;   // 0.01^2
    const float c2 = 9e-4f;   // 0.03^2
    float local = 0.f;
    for (int p = tid; p < TILE * TILE; p += 256) {
        int r = p / TILE, c = p % TILE;
        int gr = oy0 + r, gc = ox0 + c;
        if (gr < OUTD && gc < OUTD) {
            float mx = 0.f, my = 0.f, xx = 0.f, yy = 0.f, xy = 0.f;
            #pragma unroll
            for (int k = 0; k < KS; ++k) {
                float wk = w[k];
                mx += wk * hb[0][r + k][c];
                my += wk * hb[1][r + k][c];
                xx += wk * hb[2][r + k][c];
                yy += wk * hb[3][r + k][c];
                xy += wk * hb[4][r + k][c];
            }
            float mxx = mx * mx, myy = my * my, mxy = mx * my;
            float sxx = xx - mxx, syy = yy - myy, sxy = xy - mxy;
            float cs = (2.f * sxy + c2) / (sxx + syy + c2);
            float ss = (2.f * mxy + c1) / (mxx + myy + c1) * cs;
            local += ss;
        }
    }

    // ---- block reduction: wave shfl + LDS ----
    #pragma unroll
    for (int off = 32; off > 0; off >>= 1)
        local += __shfl_down(local, off, 64);
    if ((tid & 63) == 0) wred[tid >> 6] = local;
    __syncthreads();
    if (tid == 0) {
        int bid = (blockIdx.z * gridDim.y + blockIdx.y) * gridDim.x + blockIdx.x;
        partial[bid] = (double)(wred[0] + wred[1] + wred[2] + wred[3]);
    }
}

__global__ __launch_bounds__(256) void ssim_finalize(const double* __restrict__ partial,
                                                     float* __restrict__ out) {
    const int tid = threadIdx.x;
    double s = 0.0;
    for (int i = tid; i < NBLK; i += 256) s += partial[i];
    #pragma unroll
    for (int off = 32; off > 0; off >>= 1)
        s += __shfl_down(s, off, 64);
    __shared__ double sd[4];
    if ((tid & 63) == 0) sd[tid >> 6] = s;
    __syncthreads();
    if (tid == 0) {
        double total = sd[0] + sd[1] + sd[2] + sd[3];
        const double n = (double)NPLANE * OUTD * OUTD;   // 5,809,536
        out[0] = (float)(1.0 - total / n);
    }
}

extern "C" void kernel_launch(void* const* d_in, const int* in_sizes, int n_in,
                              void* d_out, int out_size, void* d_ws, size_t ws_size,
                              hipStream_t stream) {
    const float* x = (const float*)d_in[0];
    const float* y = (const float*)d_in[1];
    float* out = (float*)d_out;
    double* partial = (double*)d_ws;   // needs 6144*8 = 48 KiB

    dim3 grid(8, 8, NPLANE);
    ssim_kernel<<<grid, 256, 0, stream>>>(x, y, partial);
    ssim_finalize<<<1, 256, 0, stream>>>(partial, out);
}